// Round 2
// 775.842 us; speedup vs baseline: 1.1010x; 1.1010x over previous
//
#include <hip/hip_runtime.h>
#include <hip/hip_bf16.h>

// Problem constants
constexpr int Bc = 2, Nc = 1024, HIDc = 2048, Hc = 32, Dc = 64, HKVc = 8, NCc = 16;

typedef unsigned short bfu;  // raw bf16 bits
typedef __attribute__((ext_vector_type(8))) short frag_ab;  // 8 bf16 (4 VGPRs)
typedef __attribute__((ext_vector_type(4))) float frag_cd;  // 4 fp32 acc

__device__ __forceinline__ bfu f2bf(float f) {
  unsigned int u = __float_as_uint(f);
  unsigned int r = u + 0x7fffu + ((u >> 16) & 1u);  // RNE
  return (bfu)(r >> 16);
}
__device__ __forceinline__ ushort4 pack4(float4 v) {
  ushort4 r; r.x = f2bf(v.x); r.y = f2bf(v.y); r.z = f2bf(v.z); r.w = f2bf(v.w);
  return r;
}

// async global->LDS, 16B per lane.  HW semantics: LDS dest = wave-uniform
// base (lane 0's pointer) + lane*16B; our per-lane pointer l = base+lane*16B
// is consistent with that (lane-linear staging layout, m97 pattern).
__device__ __forceinline__ void gl16(const bfu* g, bfu* l) {
  __builtin_amdgcn_global_load_lds(
      (const __attribute__((address_space(1))) void*)g,
      (__attribute__((address_space(3))) void*)l, 16, 0, 0);
}

// ---------------------------------------------------------------------------
// Flat cast fp32 -> bf16 (4 elements/thread)
// ---------------------------------------------------------------------------
__global__ __launch_bounds__(256) void cast_bf16_k(
    const float* __restrict__ in, bfu* __restrict__ out)
{
  const size_t i = ((size_t)blockIdx.x * 256 + threadIdx.x) * 4;
  *(ushort4*)(out + i) = pack4(*(const float4*)(in + i));
}

// ---------------------------------------------------------------------------
// Transpose + cast: W fp32 [K][N] -> WT bf16 [N][K].  32x32 tiles, 256 thr.
// ---------------------------------------------------------------------------
__global__ __launch_bounds__(256) void transpose_cast_k(
    const float* __restrict__ W, bfu* __restrict__ WT, int K, int N)
{
  __shared__ float t[32][33];
  const int bn = blockIdx.x * 32, bk = blockIdx.y * 32;
  const int x = threadIdx.x & 31, y = threadIdx.x >> 5;  // 32x8
#pragma unroll
  for (int i = 0; i < 32; i += 8)
    t[y + i][x] = W[(size_t)(bk + y + i) * N + bn + x];
  __syncthreads();
#pragma unroll
  for (int i = 0; i < 32; i += 8)
    WT[(size_t)(bn + y + i) * K + bk + x] = f2bf(t[x][y + i]);
}

// ---------------------------------------------------------------------------
// Shared MFMA GEMM body (m97 structure): A bf16 [M][2048] x BT bf16 [N][2048]
// -> C fp32 [M][Nn].  128x128 tile, BK=32, 256 thr (4 waves 2x2), linear LDS,
// global_load_lds dwordx4 staging.
// ---------------------------------------------------------------------------
__device__ __forceinline__ void gemm128_gl(
    const bfu* __restrict__ A, const bfu* __restrict__ BT,
    float* __restrict__ C, const int Nn, const int m0, const int n0,
    bfu* As, bfu* Bs)
{
  const int tid = threadIdx.x;
  const int wave = tid >> 6, lane = tid & 63;
  const int wm = (wave >> 1) * 64, wn = (wave & 1) * 64;
  const int fm = lane & 15, quad = lane >> 4;
  const int sr = tid >> 2, skc = (tid & 3) * 8;  // staging row / k-col

  frag_cd acc[4][4];
#pragma unroll
  for (int i = 0; i < 4; ++i)
#pragma unroll
    for (int j = 0; j < 4; ++j) acc[i][j] = (frag_cd){0.f, 0.f, 0.f, 0.f};

  const bfu* Ag = A + (size_t)(m0 + sr) * 2048 + skc;
  const bfu* Bg = BT + (size_t)(n0 + sr) * 2048 + skc;
  bfu* Al = As + tid * 8;   // lane-linear: tid*16 bytes
  bfu* Bl = Bs + tid * 8;

  for (int k0 = 0; k0 < 2048; k0 += 32) {
    gl16(Ag + k0, Al);
    gl16(Ag + k0 + (size_t)64 * 2048, Al + 64 * 32);
    gl16(Bg + k0, Bl);
    gl16(Bg + k0 + (size_t)64 * 2048, Bl + 64 * 32);
    __syncthreads();  // compiler drains vmcnt before s_barrier
    frag_ab a[4], b[4];
#pragma unroll
    for (int im = 0; im < 4; ++im)
      a[im] = *(const frag_ab*)&As[(size_t)(wm + im * 16 + fm) * 32 + quad * 8];
#pragma unroll
    for (int in = 0; in < 4; ++in)
      b[in] = *(const frag_ab*)&Bs[(size_t)(wn + in * 16 + fm) * 32 + quad * 8];
#pragma unroll
    for (int im = 0; im < 4; ++im)
#pragma unroll
      for (int in = 0; in < 4; ++in)
        acc[im][in] = __builtin_amdgcn_mfma_f32_16x16x32_bf16(
            a[im], b[in], acc[im][in], 0, 0, 0);
    __syncthreads();
  }
#pragma unroll
  for (int im = 0; im < 4; ++im)
#pragma unroll
    for (int in = 0; in < 4; ++in) {
      const int n = n0 + wn + in * 16 + fm;
#pragma unroll
      for (int r = 0; r < 4; ++r) {
        const int m = m0 + wm + im * 16 + quad * 4 + r;
        C[(size_t)m * Nn + n] = acc[im][in][r];
      }
    }
}

// Fused Q/K/V projection: all three GEMMs in one 384-block dispatch.
// col-blocks: 0..15 -> Q (N=2048), 16..19 -> K (N=512), 20..23 -> V (N=512).
__global__ __launch_bounds__(256) void gemm_qkv_k(
    const bfu* __restrict__ A, const bfu* __restrict__ BTq,
    const bfu* __restrict__ BTk, const bfu* __restrict__ BTv,
    float* __restrict__ Cq, float* __restrict__ Ck, float* __restrict__ Cv)
{
  __shared__ __align__(16) bfu As[128 * 32];
  __shared__ __align__(16) bfu Bs[128 * 32];
  int bx = blockIdx.x;
  const bfu* BT; float* C; int Nn;
  if (bx < 16)      { BT = BTq; C = Cq; Nn = 2048; }
  else if (bx < 20) { BT = BTk; C = Ck; Nn = 512; bx -= 16; }
  else              { BT = BTv; C = Cv; Nn = 512; bx -= 20; }
  gemm128_gl(A, BT, C, Nn, blockIdx.y * 128, bx * 128, As, Bs);
}

// Output projection GEMM.
__global__ __launch_bounds__(256) void gemm_wo_k(
    const bfu* __restrict__ A, const bfu* __restrict__ BT, float* __restrict__ C)
{
  __shared__ __align__(16) bfu As[128 * 32];
  __shared__ __align__(16) bfu Bs[128 * 32];
  gemm128_gl(A, BT, C, 2048, blockIdx.y * 128, blockIdx.x * 128, As, Bs);
}

// ---------------------------------------------------------------------------
// Per-row (64-wide) softmax of k -> kl, and log_sigmoid(k)/16 -> gl.
// ---------------------------------------------------------------------------
__global__ __launch_bounds__(256) void gates64_k(
    const float* __restrict__ kin, float* __restrict__ kl, float* __restrict__ gl)
{
  const int r = blockIdx.x * 4 + (threadIdx.x >> 6);
  const int lane = threadIdx.x & 63;
  const size_t idx = (size_t)r * 64 + lane;
  const float x = kin[idx];
  float m = x;
#pragma unroll
  for (int o = 32; o > 0; o >>= 1) m = fmaxf(m, __shfl_xor(m, o, 64));
  const float e = __expf(x - m);
  float s = e;
#pragma unroll
  for (int o = 32; o > 0; o >>= 1) s += __shfl_xor(s, o, 64);
  kl[idx] = e / s;
  const float ls = fminf(x, 0.f) - log1pf(__expf(-fabsf(x)));
  gl[idx] = ls * 0.0625f;
}

// ---------------------------------------------------------------------------
// Per (b,hkv,chunk): triangular solves.  256 blocks.
// ---------------------------------------------------------------------------
__global__ __launch_bounds__(256) void chunk_prep_k(
    const float* __restrict__ kl, const float* __restrict__ v,
    const float* __restrict__ gl, float* __restrict__ u_out, float* __restrict__ w_out)
{
  __shared__ float KC[64][65];
  __shared__ float KB[64][65];
  __shared__ float VB[64][65];
  const int blk = blockIdx.x;
  const int c = blk & 15, bh = blk >> 4;
  const int hk = bh & 7, b = bh >> 3;
  const int tid = threadIdx.x;
  for (int x = tid; x < 4096; x += 256) {
    const int i = x >> 6, d = x & 63;
    const size_t src = ((size_t)(b * Nc + c * 64 + i) * 8 + hk) * 64 + d;
    const float kv = kl[src], g = gl[src], vv = v[src];
    KC[i][d] = kv; KB[i][d] = kv * g; VB[i][d] = vv * g;
  }
  __syncthreads();
  float Lreg[16];
#pragma unroll
  for (int e = 0; e < 16; ++e) {
    const int x = e * 256 + tid;
    const int i = x >> 6, j = x & 63;
    float acc = 0.f;
    if (j < i) {
      for (int d = 0; d < 64; ++d) acc += KB[i][d] * KC[j][d];
    }
    Lreg[e] = acc;
  }
  __syncthreads();
#pragma unroll
  for (int e = 0; e < 16; ++e) {
    const int x = e * 256 + tid;
    KC[x >> 6][x & 63] = Lreg[e];
  }
  __syncthreads();
  if (tid < 128) {
    const int d = tid & 63;
    float (*X)[65] = (tid < 64) ? VB : KB;
    for (int i = 1; i < 64; ++i) {
      float acc = X[i][d];
      for (int j = 0; j < i; ++j) acc -= KC[i][j] * X[j][d];
      X[i][d] = acc;
    }
  }
  __syncthreads();
  for (int x = tid; x < 4096; x += 256) {
    u_out[(size_t)blk * 4096 + x] = VB[x >> 6][x & 63];
    w_out[(size_t)blk * 4096 + x] = KB[x >> 6][x & 63];
  }
}

// ---------------------------------------------------------------------------
// Serial scan over chunks per (b,hkv).  16 blocks x 512 threads.
// 3 barriers/chunk: kl staged into its own tile alongside w; u_ps prefetched
// into registers before the first barrier so global latency overlaps compute.
// ---------------------------------------------------------------------------
__global__ __launch_bounds__(512) void scan_k(
    const float* __restrict__ u_ps, const float* __restrict__ w_ps,
    const float* __restrict__ kl, float* __restrict__ u_p, float* __restrict__ S_pre)
{
  __shared__ float S[64][64];
  __shared__ float kw[64][64];
  __shared__ float kt[64][64];
  __shared__ float up[64][72];
  const int blk = blockIdx.x;
  const int hk = blk & 7, b = blk >> 3;
  const int t = threadIdx.x;
  const int row = t >> 3;
  const int c0 = (t & 7) * 8;
  for (int x = t; x < 4096; x += 512) S[x >> 6][x & 63] = 0.f;
  __syncthreads();
  for (int c = 0; c < 16; ++c) {
    const size_t cb = ((size_t)blk * 16 + c) * 4096;
    // prefetch this chunk's u_ps slice into registers (no dependence on S)
    float upre[8];
    {
      const float* ug = u_ps + cb + row * 64 + c0;
#pragma unroll
      for (int j = 0; j < 8; ++j) upre[j] = ug[j];
    }
    // stage w and kl tiles; spill S_pre
    for (int x = t; x < 4096; x += 512) {
      const int i = x >> 6, d = x & 63;
      S_pre[cb + x] = S[i][d];
      kw[i][d] = w_ps[cb + x];
      kt[i][d] = kl[((size_t)(b * Nc + c * 64 + i) * 8 + hk) * 64 + d];
    }
    __syncthreads();
    {
      float acc[8];
#pragma unroll
      for (int j = 0; j < 8; ++j) acc[j] = upre[j];
      for (int e = 0; e < 64; ++e) {
        const float wv = kw[row][e];
#pragma unroll
        for (int j = 0; j < 8; ++j) acc[j] -= wv * S[e][c0 + j];
      }
      float* upg = u_p + cb + row * 64 + c0;
#pragma unroll
      for (int j = 0; j < 8; ++j) { up[row][c0 + j] = acc[j]; upg[j] = acc[j]; }
    }
    __syncthreads();
    {
      float sacc[8];
#pragma unroll
      for (int j = 0; j < 8; ++j) sacc[j] = S[row][c0 + j];
      for (int i = 0; i < 64; ++i) {
        const float kv = kt[i][row];
#pragma unroll
        for (int j = 0; j < 8; ++j) sacc[j] += kv * up[i][c0 + j];
      }
#pragma unroll
      for (int j = 0; j < 8; ++j) S[row][c0 + j] = sacc[j];
    }
    __syncthreads();
  }
}

// ---------------------------------------------------------------------------
// o_lin per (b,h,chunk).  1024 blocks.
// ---------------------------------------------------------------------------
__global__ __launch_bounds__(256) void olin_k(
    const float* __restrict__ qraw, const float* __restrict__ kl,
    const float* __restrict__ upb, const float* __restrict__ S_pre,
    float* __restrict__ o_comb)
{
  __shared__ float Q[64][65];
  __shared__ __align__(16) float Bb[64][68];
  __shared__ float At[64][65];
  const int blk = blockIdx.x;
  const int c = blk & 15, bh = blk >> 4;
  const int h = bh & 31, b = bh >> 5, hk = h >> 2;
  const int tid = threadIdx.x;
  const int i = tid >> 2, d0 = (tid & 3) * 16;
  for (int x = tid; x < 4096; x += 256) {
    const int r = x >> 6, d = x & 63;
    Q[r][d] = qraw[((size_t)(b * Nc + c * 64 + r) * 32 + h) * 64 + d];
    Bb[r][d] = kl[((size_t)(b * Nc + c * 64 + r) * 8 + hk) * 64 + d];
  }
  __syncthreads();
  {
    float mx = -1e30f;
#pragma unroll
    for (int j = 0; j < 16; ++j) mx = fmaxf(mx, Q[i][d0 + j]);
#pragma unroll
    for (int o = 1; o < 4; o <<= 1) mx = fmaxf(mx, __shfl_xor(mx, o, 64));
    float ev[16];
    float sum = 0.f;
#pragma unroll
    for (int j = 0; j < 16; ++j) { ev[j] = __expf(Q[i][d0 + j] - mx); sum += ev[j]; }
#pragma unroll
    for (int o = 1; o < 4; o <<= 1) sum += __shfl_xor(sum, o, 64);
    const float inv = 1.f / sum;
#pragma unroll
    for (int j = 0; j < 16; ++j) Q[i][d0 + j] = ev[j] * inv;
  }
  {
    float a[16];
#pragma unroll
    for (int j = 0; j < 16; ++j) a[j] = 0.f;
    for (int d = 0; d < 64; ++d) {
      const float qv = Q[i][d];
#pragma unroll
      for (int j = 0; j < 16; ++j) a[j] += qv * Bb[d0 + j][d];
    }
#pragma unroll
    for (int j = 0; j < 16; ++j) At[i][d0 + j] = (d0 + j <= i) ? a[j] : 0.f;
  }
  __syncthreads();
  const size_t cb = ((size_t)(b * 8 + hk) * 16 + c) * 4096;
  for (int x = tid; x < 4096; x += 256) Bb[x >> 6][x & 63] = S_pre[cb + x];
  __syncthreads();
  float o[16];
#pragma unroll
  for (int j = 0; j < 16; ++j) o[j] = 0.f;
  for (int e = 0; e < 64; ++e) {
    const float qv = Q[i][e];
#pragma unroll
    for (int j = 0; j < 16; ++j) o[j] += qv * Bb[e][d0 + j];
  }
  __syncthreads();
  for (int x = tid; x < 4096; x += 256) Bb[x >> 6][x & 63] = upb[cb + x];
  __syncthreads();
  for (int j2 = 0; j2 < 64; ++j2) {
    const float av = At[i][j2];
#pragma unroll
    for (int j = 0; j < 16; ++j) o[j] += av * Bb[j2][d0 + j];
  }
  float* oc = o_comb + ((size_t)(b * Nc + c * 64 + i) * 32 + h) * 64 + d0;
#pragma unroll
  for (int j = 0; j < 16; ++j) oc[j] = 0.5f * o[j];
}

// ---------------------------------------------------------------------------
// Base attention pass A (MFMA): online m,l only, no score writes.
// S^T orientation: A = K (m=j), B = Q (n=i), k = d.  1024 blocks x 256 thr.
// ---------------------------------------------------------------------------
__global__ __launch_bounds__(256) void ml_mfma_k(
    const float* __restrict__ qraw, const float* __restrict__ kraw,
    float* __restrict__ mbuf, float* __restrict__ lbuf)
{
  constexpr int LDK = 72;
  __shared__ __align__(16) bfu Qt[64 * LDK];  // [i][d]
  __shared__ __align__(16) bfu Kt[64 * LDK];  // [j][d]
  __shared__ float mred[4][64];
  __shared__ float lred[4][64];
  const int blk = blockIdx.x;
  const int ib = blk & 15, bh = blk >> 4;
  const int h = bh & 31, b = bh >> 5, hk = h >> 2;
  const int tid = threadIdx.x;
  const int wave = tid >> 6, lane = tid & 63;
  const int fm = lane & 15, quad = lane >> 4;
  const int wj = wave * 16;
  const int srow = tid >> 2, sd0 = (tid & 3) * 16;

  // stage Qt [i][d] bf16
  {
    const float* qp = qraw + ((size_t)(b * Nc + ib * 64 + srow) * 32 + h) * 64 + sd0;
    bfu* dst = &Qt[(size_t)srow * LDK + sd0];
#pragma unroll
    for (int e = 0; e < 4; ++e)
      *(ushort4*)(dst + e * 4) = pack4(*(const float4*)(qp + e * 4));
  }
  __syncthreads();
  // Q B-frags: [n = in*16+fm][k = kk*32 + quad*8], loaded once
  frag_ab qb[4][2];
#pragma unroll
  for (int in = 0; in < 4; ++in)
#pragma unroll
    for (int kk = 0; kk < 2; ++kk)
      qb[in][kk] = *(const frag_ab*)&Qt[(size_t)(in * 16 + fm) * LDK + kk * 32 + quad * 8];

  float m[4], l[4];
#pragma unroll
  for (int in = 0; in < 4; ++in) { m[in] = -1e30f; l[in] = 0.f; }

  for (int jt = 0; jt <= ib; ++jt) {
    __syncthreads();
    {
      const float* kp = kraw + ((size_t)(b * Nc + jt * 64 + srow) * 8 + hk) * 64 + sd0;
      bfu* dst = &Kt[(size_t)srow * LDK + sd0];
#pragma unroll
      for (int e = 0; e < 4; ++e)
        *(ushort4*)(dst + e * 4) = pack4(*(const float4*)(kp + e * 4));
    }
    __syncthreads();
    frag_ab ka[2];
    ka[0] = *(const frag_ab*)&Kt[(size_t)(wj + fm) * LDK + quad * 8];
    ka[1] = *(const frag_ab*)&Kt[(size_t)(wj + fm) * LDK + 32 + quad * 8];
    const bool diag = (jt == ib);
#pragma unroll
    for (int in = 0; in < 4; ++in) {
      frag_cd acc = (frag_cd){0.f, 0.f, 0.f, 0.f};
      acc = __builtin_amdgcn_mfma_f32_16x16x32_bf16(ka[0], qb[in][0], acc, 0, 0, 0);
      acc = __builtin_amdgcn_mfma_f32_16x16x32_bf16(ka[1], qb[in][1], acc, 0, 0, 0);
      // lane holds S^T[j = wj+quad*4+r][i = in*16+fm]
      const int iloc = in * 16 + fm;
      float sv[4];
      bool vd[4];
      float tm = -1e30f;
#pragma unroll
      for (int r = 0; r < 4; ++r) {
        const int jloc = wj + quad * 4 + r;
        vd[r] = !diag || (jloc <= iloc);
        sv[r] = acc[r] * 0.125f;
        if (vd[r]) tm = fmaxf(tm, sv[r]);
      }
      const float mn = fmaxf(m[in], tm);
      float lsum = 0.f;
#pragma unroll
      for (int r = 0; r < 4; ++r)
        if (vd[r]) lsum += __expf(sv[r] - mn);
      l[in] = l[in] * __expf(m[in] - mn) + lsum;  // l==0 when m==-1e30, safe
      m[in] = mn;
    }
  }
  // reduce across quads (lanes fm fixed, quad varies): offsets 16, 32
#pragma unroll
  for (int in = 0; in < 4; ++in) {
    float mm = m[in], ll = l[in];
#pragma unroll
    for (int off = 16; off < 64; off <<= 1) {
      const float mo = __shfl_xor(mm, off, 64);
      const float lo = __shfl_xor(ll, off, 64);
      const float mn = fmaxf(mm, mo);
      ll = ll * __expf(mm - mn) + lo * __expf(mo - mn);
      mm = mn;
    }
    if (quad == 0) { mred[wave][in * 16 + fm] = mm; lred[wave][in * 16 + fm] = ll; }
  }
  __syncthreads();
  if (tid < 64) {
    float M = -1e30f;
#pragma unroll
    for (int w = 0; w < 4; ++w) M = fmaxf(M, mred[w][tid]);
    float L = 0.f;
#pragma unroll
    for (int w = 0; w < 4; ++w) L += lred[w][tid] * __expf(mred[w][tid] - M);
    const size_t rowi = (size_t)(b * 32 + h) * 1024 + ib * 64 + tid;
    mbuf[rowi] = M;
    lbuf[rowi] = L;
  }
}

// ---------------------------------------------------------------------------
// Base attention pass B (MFMA): recompute scores, p = exp(s-m)/l -> attn
// (fp32, zero above diagonal), PV via MFMA (P staged bf16, V^T staged bf16).
// Writes oc_bf = bf16(o_comb + 0.5*o_base) directly (final-GEMM input),
// removing the separate cast dispatch.  1024 blocks x 256 threads.
// ---------------------------------------------------------------------------
__global__ __launch_bounds__(256) void pv_mfma_k(
    const float* __restrict__ qraw, const float* __restrict__ kraw,
    const float* __restrict__ vraw, const float* __restrict__ mbuf,
    const float* __restrict__ lbuf, float* __restrict__ attn,
    const float* __restrict__ o_comb, bfu* __restrict__ oc_bf)
{
  constexpr int LDK = 72;
  __shared__ __align__(16) bfu Qt[64 * LDK];    // [i][d]
  __shared__ __align__(16) bfu Kt[64 * LDK];    // [j][d]
  __shared__ __align__(16) bfu Vt[64 * LDK];    // [dv][j]  (transposed)
  __shared__ __align__(16) bfu Pmat[64 * LDK];  // [i][j]
  const int blk = blockIdx.x;
  const int ib = blk & 15, bh = blk >> 4;
  const int h = bh & 31, b = bh >> 5, hk = h >> 2;
  const int tid = threadIdx.x;
  const int wave = tid >> 6, lane = tid & 63;
  const int fm = lane & 15, quad = lane >> 4;
  const int wj = wave * 16;   // score phase: wave's j slice
  const int im0 = wave * 16;  // PV phase: wave's i slice
  const int srow = tid >> 2, sd0 = (tid & 3) * 16;

  // stage Qt
  {
    const float* qp = qraw + ((size_t)(b * Nc + ib * 64 + srow) * 32 + h) * 64 + sd0;
    bfu* dst = &Qt[(size_t)srow * LDK + sd0];
#pragma unroll
    for (int e = 0; e < 4; ++e)
      *(ushort4*)(dst + e * 4) = pack4(*(const float4*)(qp + e * 4));
  }
  __syncthreads();
  frag_ab qb[4][2];
#pragma unroll
  for (int in = 0; in < 4; ++in)
#pragma unroll
    for (int kk = 0; kk < 2; ++kk)
      qb[in][kk] = *(const frag_ab*)&Qt[(size_t)(in * 16 + fm) * LDK + kk * 32 + quad * 8];

  // per-lane m, 1/l for its 4 i's (i = in*16+fm), constant across jt
  float mi[4], il[4];
#pragma unroll
  for (int in = 0; in < 4; ++in) {
    const size_t rowi = (size_t)(b * 32 + h) * 1024 + ib * 64 + in * 16 + fm;
    mi[in] = mbuf[rowi];
    il[in] = 1.f / lbuf[rowi];
  }

  float* arow0 = attn + ((size_t)(b * 32 + h) * 1024 + ib * 64) * 1024;

  frag_cd o[4];
#pragma unroll
  for (int in = 0; in < 4; ++in) o[in] = (frag_cd){0.f, 0.f, 0.f, 0.f};

  for (int jt = 0; jt <= ib; ++jt) {
    __syncthreads();  // protect prev iter's Vt/Pmat reads
    // stage Kt [j][d]
    {
      const float* kp = kraw + ((size_t)(b * Nc + jt * 64 + srow) * 8 + hk) * 64 + sd0;
      bfu* dst = &Kt[(size_t)srow * LDK + sd0];
#pragma unroll
      for (int e = 0; e < 4; ++e)
        *(ushort4*)(dst + e * 4) = pack4(*(const float4*)(kp + e * 4));
    }
    // stage Vt [dv][j] via register 4x4 transpose
    {
      const int jg = (tid & 15) * 4, dvg = (tid >> 4) * 4;
      float4 rv[4];
#pragma unroll
      for (int rr = 0; rr < 4; ++rr)
        rv[rr] = *(const float4*)(vraw + ((size_t)(b * Nc + jt * 64 + jg + rr) * 8 + hk) * 64 + dvg);
#pragma unroll
      for (int e = 0; e < 4; ++e) {
        ushort4 w;
        w.x = f2bf(((const float*)&rv[0])[e]);
        w.y = f2bf(((const float*)&rv[1])[e]);
        w.z = f2bf(((const float*)&rv[2])[e]);
        w.w = f2bf(((const float*)&rv[3])[e]);
        *(ushort4*)&Vt[(size_t)(dvg + e) * LDK + jg] = w;
      }
    }
    __syncthreads();
    // scores S^T: A = K rows (wave's j slice), B = Q
    frag_ab ka[2];
    ka[0] = *(const frag_ab*)&Kt[(size_t)(wj + fm) * LDK + quad * 8];
    ka[1] = *(const frag_ab*)&Kt[(size_t)(wj + fm) * LDK + 32 + quad * 8];
    const bool diag = (jt == ib);
#pragma unroll
    for (int in = 0; in < 4; ++in) {
      frag_cd acc = (frag_cd){0.f, 0.f, 0.f, 0.f};
      acc = __builtin_amdgcn_mfma_f32_16x16x32_bf16(ka[0], qb[in][0], acc, 0, 0, 0);
      acc = __builtin_amdgcn_mfma_f32_16x16x32_bf16(ka[1], qb[in][1], acc, 0, 0, 0);
      const int iloc = in * 16 + fm;
      float p[4];
#pragma unroll
      for (int r = 0; r < 4; ++r) {
        const int jloc = wj + quad * 4 + r;
        const bool vdr = !diag || (jloc <= iloc);
        p[r] = vdr ? __expf(acc[r] * 0.125f - mi[in]) * il[in] : 0.f;
      }
      // write p to attn: row iloc, 4 consecutive cols jt*64 + wj + quad*4
      *(float4*)(arow0 + (size_t)iloc * 1024 + jt * 64 + wj + quad * 4) =
          make_float4(p[0], p[1], p[2], p[3]);
      // stage p into Pmat [i][j] bf16
      ushort4 w;
      w.x = f2bf(p[0]); w.y = f2bf(p[1]); w.z = f2bf(p[2]); w.w = f2bf(p[3]);
      *(ushort4*)&Pmat[(size_t)iloc * LDK + wj + quad * 4] = w;
    }
    __syncthreads();
    // PV: A = Pmat rows (wave's i slice), B = Vt rows (dv), k = j
    frag_ab pa[2];
    pa[0] = *(const frag_ab*)&Pmat[(size_t)(im0 + fm) * LDK + quad * 8];
    pa[1] = *(const frag_ab*)&Pmat[(size_t)(im0 + fm) * LDK + 32 + quad * 8];
#pragma unroll
    for (int in = 0; in < 4; ++in) {
      frag_ab vb0 = *(const frag_ab*)&Vt[(size_t)(in * 16 + fm) * LDK + quad * 8];
      frag_ab vb1 = *(const frag_ab*)&Vt[(size_t)(in * 16 + fm) * LDK + 32 + quad * 8];
      o[in] = __builtin_amdgcn_mfma_f32_16x16x32_bf16(pa[0], vb0, o[in], 0, 0, 0);
      o[in] = __builtin_amdgcn_mfma_f32_16x16x32_bf16(pa[1], vb1, o[in], 0, 0, 0);
    }
  }
  // zero-fill non-causal tiles of attn
  for (int jt2 = ib + 1; jt2 < 16; ++jt2) {
    const float4 z = make_float4(0.f, 0.f, 0.f, 0.f);
    for (int x = tid; x < 1024; x += 256) {
      const int row = x >> 4, c4 = (x & 15) * 4;
      *(float4*)(arow0 + (size_t)row * 1024 + jt2 * 64 + c4) = z;
    }
  }
  // oc_bf = bf16(o_comb + 0.5*o)   (o: row i = im0+quad*4+r, col dv = in*16+fm)
#pragma unroll
  for (int in = 0; in < 4; ++in)
#pragma unroll
    for (int r = 0; r < 4; ++r) {
      const int i = im0 + quad * 4 + r;
      const size_t idx = ((size_t)(b * Nc + ib * 64 + i) * 32 + h) * 64 + in * 16 + fm;
      oc_bf[idx] = f2bf(o_comb[idx] + 0.5f * o[in][r]);
    }
}

// ---------------------------------------------------------------------------
extern "C" void kernel_launch(void* const* d_in, const int* in_sizes, int n_in,
                              void* d_out, int out_size, void* d_ws, size_t ws_size,
                              hipStream_t stream) {
  const float* hs = (const float*)d_in[0];
  const float* Wq = (const float*)d_in[1];
  const float* Wk = (const float*)d_in[2];
  const float* Wv = (const float*)d_in[3];
  const float* Wo = (const float*)d_in[4];
  float* out = (float*)d_out;                      // [B,N,HID]
  float* attn = out + (size_t)Bc * Nc * HIDc;      // [B,H,N,N]

  float* ws = (float*)d_ws;
  float* q_raw  = ws;                     // 4,194,304 f32
  float* k_raw  = q_raw + 4194304;        // 1,048,576
  float* v_raw  = k_raw + 1048576;        // 1,048,576
  float* kl     = v_raw + 1048576;        // 1,048,576
  float* gl     = kl + 1048576;           // 1,048,576
  float* u_ps   = gl + 1048576;           // 2,097,152
  float* w_ps   = u_ps + 2097152;         // 2,097,152
  float* upb    = w_ps + 2097152;         // 2,097,152
  float* S_pre  = upb + 2097152;          // 2,097,152
  float* o_comb = S_pre + 2097152;        // 4,194,304
  float* mbuf   = o_comb + 4194304;       // 65,536
  float* lbuf   = mbuf + 65536;           // 65,536
  bfu* bstart = (bfu*)(lbuf + 65536);
  bfu* hs_bf  = bstart;                   // 4,194,304 bf16
  bfu* WqT    = hs_bf + 4194304;          // 4,194,304
  bfu* WkT    = WqT + 4194304;            // 1,048,576
  bfu* WvT    = WkT + 1048576;            // 1,048,576
  bfu* WoT    = WvT + 1048576;            // 4,194,304
  bfu* oc_bf  = WoT + 4194304;            // 4,194,304

  // Casts / weight transposes
  cast_bf16_k<<<4096, 256, 0, stream>>>(hs, hs_bf);
  transpose_cast_k<<<dim3(64, 64), 256, 0, stream>>>(Wq, WqT, 2048, 2048);
  transpose_cast_k<<<dim3(16, 64), 256, 0, stream>>>(Wk, WkT, 2048, 512);
  transpose_cast_k<<<dim3(16, 64), 256, 0, stream>>>(Wv, WvT, 2048, 512);
  transpose_cast_k<<<dim3(64, 64), 256, 0, stream>>>(Wo, WoT, 2048, 2048);
  // Fused Q/K/V projection (bf16 MFMA, global_load_lds staging, 384 blocks)
  gemm_qkv_k<<<dim3(24, 16), 256, 0, stream>>>(hs_bf, WqT, WkT, WvT,
                                               q_raw, k_raw, v_raw);
  // Gates / feature maps
  gates64_k<<<4096, 256, 0, stream>>>(k_raw, kl, gl);
  // Delta-rule
  chunk_prep_k<<<256, 256, 0, stream>>>(kl, v_raw, gl, u_ps, w_ps);
  scan_k<<<16, 512, 0, stream>>>(u_ps, w_ps, kl, upb, S_pre);
  // Linear-attention output (writes o_comb = 0.5*o_lin)
  olin_k<<<1024, 256, 0, stream>>>(q_raw, kl, upb, S_pre, o_comb);
  // Base causal attention: MFMA m,l pass then fused p/attn-write/PV pass
  ml_mfma_k<<<1024, 256, 0, stream>>>(q_raw, k_raw, mbuf, lbuf);
  pv_mfma_k<<<1024, 256, 0, stream>>>(q_raw, k_raw, v_raw, mbuf, lbuf, attn,
                                      o_comb, oc_bf);
  // Output projection (reads bf16 written by pv_mfma_k)
  gemm_wo_k<<<dim3(16, 16), 256, 0, stream>>>(oc_bf, WoT, out);
}